// Round 10
// baseline (799.979 us; speedup 1.0000x reference)
//
#include <hip/hip_runtime.h>
#include <hip/hip_cooperative_groups.h>

namespace cg = cooperative_groups;

// SharedSparseMoEBlock on gfx950 — round 10: cooperative mega-kernel WITH
// checked launch + fallback to the proven r7 multi-kernel chain.
// Mega phases are r7-identical (no r8 spill trap).

typedef __bf16 bf16x8 __attribute__((ext_vector_type(8)));
typedef unsigned short u16x8 __attribute__((ext_vector_type(8)));
typedef float f32x4 __attribute__((ext_vector_type(4)));

#define HWP 9216
#define NPIX 73728
#define LDX 136
#define LDH 136
#define MAXSLOTS 77312
#define MAXTILES 1208
#define NB 512

__device__ __forceinline__ unsigned short f2bf(float f) {
    unsigned u = __float_as_uint(f);
    u += 0x7fffu + ((u >> 16) & 1u);   // RNE
    return (unsigned short)(u >> 16);
}

__device__ __forceinline__ unsigned pk_bf16(float a, float b) {
    return (unsigned)f2bf(a) | ((unsigned)f2bf(b) << 16);
}

__device__ __forceinline__ float bf2f(unsigned short h) {
    return __uint_as_float((unsigned)h << 16);
}

__device__ __forceinline__ float fast_gelu(float x) {
    float x2 = x * x;
    float u = x * fmaf(0.0356774081f, x2, 0.7978845608f);
    float e = __builtin_amdgcn_exp2f(u * 2.8853900818f);
    float r = __builtin_amdgcn_rcpf(e + 1.0f);
    float t = fmaf(-2.0f, r, 1.0f);
    float s = 0.5f * x;
    return fmaf(s, t, s);
}

__device__ __forceinline__ f32x4 mfma16(u16x8 a, u16x8 b, f32x4 c) {
    return __builtin_amdgcn_mfma_f32_16x16x32_bf16(
        __builtin_bit_cast(bf16x8, a), __builtin_bit_cast(bf16x8, b), c, 0, 0, 0);
}

// ---------------- shared device routines ----------------

__device__ void router_body(
    int blk, int tid,
    const float* __restrict__ x, const float* __restrict__ gb,
    const float* gws, unsigned short* xls, float* part,
    unsigned short* __restrict__ xT,
    int* __restrict__ pixmask, float* __restrict__ pixw3,
    int* __restrict__ pixaux, int* __restrict__ bincount,
    float* __restrict__ accum)
{
    const int b = blk / 144;
    const int p0 = (blk - b * 144) * 64;
    const int p = tid & 63, q = tid >> 6;
    const float* xb = x + (size_t)b * 128 * HWP + p0 + p;

    float lg[8];
    #pragma unroll
    for (int e = 0; e < 8; ++e) lg[e] = 0.f;
    #pragma unroll
    for (int k = 0; k < 32; ++k) {
        int c = q * 32 + k;
        float xv = xb[(size_t)c * HWP];
        xls[p * 132 + c] = f2bf(xv);
        #pragma unroll
        for (int e = 0; e < 8; ++e) lg[e] = fmaf(xv, gws[e * 128 + c], lg[e]);
    }
    #pragma unroll
    for (int e = 0; e < 8; ++e) part[(q * 64 + p) * 8 + e] = lg[e];
    __syncthreads();

    if (tid < 64) {
        const int gp = b * HWP + p0 + tid;
        float l2[8];
        #pragma unroll
        for (int e = 0; e < 8; ++e)
            l2[e] = gb[e] + part[tid * 8 + e] + part[(64 + tid) * 8 + e]
                  + part[(128 + tid) * 8 + e] + part[(192 + tid) * 8 + e];
        float mx = l2[0];
        #pragma unroll
        for (int e = 1; e < 8; ++e) mx = fmaxf(mx, l2[e]);
        float pr[8]; float s = 0.f;
        #pragma unroll
        for (int e = 0; e < 8; ++e) { pr[e] = __expf(l2[e] - mx); s += pr[e]; }
        float sinv = __builtin_amdgcn_rcpf(s);
        #pragma unroll
        for (int e = 0; e < 8; ++e) pr[e] *= sinv;

        unsigned chosen = 0; float topsum = 0.f;
        for (int k = 0; k < 3; ++k) {
            int best = 0; float bv = -1.f;
            #pragma unroll
            for (int e = 0; e < 8; ++e) {
                bool ok = !((chosen >> e) & 1u) && pr[e] > bv;
                bv = ok ? pr[e] : bv;
                best = ok ? e : best;
            }
            chosen |= 1u << best;
            topsum += bv;
        }
        float tinv = __builtin_amdgcn_rcpf(topsum);

        pixmask[gp] = (int)chosen;
        {
            int j = 0;
            #pragma unroll
            for (int e = 0; e < 8; ++e)
                if ((chosen >> e) & 1u) { pixw3[gp * 3 + j] = pr[e] * tinv; ++j; }
        }

        unsigned long long eq = ~0ull;
        #pragma unroll
        for (int bit = 0; bit < 8; ++bit) {
            unsigned long long bb = __ballot((chosen >> bit) & 1u);
            eq &= ((chosen >> bit) & 1u) ? bb : ~bb;
        }
        const unsigned long long lowmask = (tid == 0) ? 0ull : (~0ull >> (64 - tid));
        int rank = __popcll(eq & lowmask);
        int cnt = __popcll(eq);
        int leader = __ffsll((unsigned long long)eq) - 1;
        int off_val = 0;
        if (rank == 0) off_val = atomicAdd(&bincount[chosen], cnt);
        int binoff = __shfl(off_val, leader);
        pixaux[gp] = binoff + rank;

        #pragma unroll
        for (int e = 0; e < 8; ++e) {
            float v = pr[e];
            float c2 = ((chosen >> e) & 1u) ? 1.f : 0.f;
            #pragma unroll
            for (int off = 32; off > 0; off >>= 1) {
                v += __shfl_down(v, off);
                c2 += __shfl_down(c2, off);
            }
            if (tid == 0) {
                atomicAdd(&accum[e], v);
                atomicAdd(&accum[8 + e], c2);
            }
        }
    }

    {   // xT write (xls stable since the barrier)
        const int pp = tid >> 2, qq = tid & 3;
        unsigned short* dst = xT + ((size_t)blk * 64 + pp) * 128 + qq * 32;
        const unsigned short* src = &xls[pp * 132 + qq * 32];
        #pragma unroll
        for (int j = 0; j < 4; ++j)
            *(u16x8*)(dst + j * 8) = *(const u16x8*)(src + j * 8);
    }
}

__device__ void moe_tile_body(
    int mask, int base, int tid,
    const unsigned short* __restrict__ xT, const int* __restrict__ idx,
    const float* __restrict__ pixw3,
    const unsigned short* __restrict__ wbf,
    const float* __restrict__ sb1, const float* __restrict__ sb2,
    const float* __restrict__ eb1, const float* __restrict__ eb2,
    unsigned short* xs, unsigned short* hs, float* wls,
    unsigned short* __restrict__ outT)
{
    {   // gather 64 pixel rows from xT
        const int p = tid >> 2, q = tid & 3;
        const int gp = idx[base + p];
        const unsigned short* src = xT + (size_t)gp * 128 + q * 32;
        unsigned short* dst = &xs[p * LDX + q * 32];
        #pragma unroll
        for (int j = 0; j < 4; ++j)
            *(u16x8*)(dst + j * 8) = *(const u16x8*)(src + j * 8);
        if (q == 0) {
            wls[p * 4 + 0] = pixw3[gp * 3 + 0];
            wls[p * 4 + 1] = pixw3[gp * 3 + 1];
            wls[p * 4 + 2] = pixw3[gp * 3 + 2];
        }
    }
    __syncthreads();

    int el[3];
    { int n = 0;
      #pragma unroll
      for (int e = 0; e < 8; ++e) if ((mask >> e) & 1) { if (n < 3) el[n] = e; ++n; } }

    const int wave = tid >> 6;
    const int lr = tid & 15;
    const int lq = (tid >> 4) & 3;

    const f32x4 vzero = {0.f, 0.f, 0.f, 0.f};
    f32x4 fin[2][4];
    #pragma unroll
    for (int t2 = 0; t2 < 2; ++t2)
        #pragma unroll
        for (int nt2 = 0; nt2 < 4; ++nt2) fin[t2][nt2] = vzero;

    for (int pass = 0; pass < 4; ++pass) {
        const unsigned short* w1; const unsigned short* w2;
        const float* b1; const float* b2;
        if (pass == 0) { w1 = wbf; b1 = sb1; w2 = wbf + 65536; b2 = sb2; }
        else {
            int e = el[pass - 1];
            w1 = wbf + 131072 + (size_t)e * (512 * 128);  b1 = eb1 + e * 512;
            w2 = wbf + 655360 + (size_t)e * (128 * 512);  b2 = eb2 + e * 128;
        }

        f32x4 tmp[2][4];
        #pragma unroll
        for (int t2 = 0; t2 < 2; ++t2)
            #pragma unroll
            for (int nt2 = 0; nt2 < 4; ++nt2) tmp[t2][nt2] = vzero;

        for (int chunk = 0; chunk < 4; ++chunk) {
            u16x8 w1f[2][4];
            #pragma unroll
            for (int t2 = 0; t2 < 2; ++t2) {
                const int hid0 = chunk * 128 + wave * 32 + t2 * 16;
                const u16x8* wr = (const u16x8*)(w1 + (size_t)(hid0 + lr) * 128) + lq;
                #pragma unroll
                for (int ks = 0; ks < 4; ++ks) w1f[t2][ks] = wr[ks * 4];
            }
            f32x4 acc[2][4];
            #pragma unroll
            for (int t2 = 0; t2 < 2; ++t2)
                #pragma unroll
                for (int nt2 = 0; nt2 < 4; ++nt2) acc[t2][nt2] = vzero;
            #pragma unroll
            for (int ks = 0; ks < 4; ++ks) {
                #pragma unroll
                for (int nt2 = 0; nt2 < 4; ++nt2) {
                    u16x8 xf = *(const u16x8*)&xs[(nt2 * 16 + lr) * LDX + ks * 32 + lq * 8];
                    acc[0][nt2] = mfma16(w1f[0][ks], xf, acc[0][nt2]);
                    acc[1][nt2] = mfma16(w1f[1][ks], xf, acc[1][nt2]);
                }
            }
            #pragma unroll
            for (int t2 = 0; t2 < 2; ++t2) {
                const int hl = wave * 32 + t2 * 16 + lq * 4;
                const f32x4 b1v = *(const f32x4*)&b1[chunk * 128 + hl];
                #pragma unroll
                for (int nt2 = 0; nt2 < 4; ++nt2) {
                    float g0 = fast_gelu(acc[t2][nt2][0] + b1v[0]);
                    float g1 = fast_gelu(acc[t2][nt2][1] + b1v[1]);
                    float g2 = fast_gelu(acc[t2][nt2][2] + b1v[2]);
                    float g3 = fast_gelu(acc[t2][nt2][3] + b1v[3]);
                    uint2 wv = {pk_bf16(g0, g1), pk_bf16(g2, g3)};
                    *(uint2*)&hs[(nt2 * 16 + lr) * LDH + hl] = wv;
                }
            }
            __syncthreads();
            u16x8 w2f[2][4];
            #pragma unroll
            for (int t2 = 0; t2 < 2; ++t2) {
                const int c0 = wave * 32 + t2 * 16;
                const u16x8* wr = (const u16x8*)(w2 + (size_t)(c0 + lr) * 512 + chunk * 128) + lq;
                #pragma unroll
                for (int ks = 0; ks < 4; ++ks) w2f[t2][ks] = wr[ks * 4];
            }
            #pragma unroll
            for (int ks = 0; ks < 4; ++ks) {
                #pragma unroll
                for (int nt2 = 0; nt2 < 4; ++nt2) {
                    u16x8 hb = *(const u16x8*)&hs[(nt2 * 16 + lr) * LDH + ks * 32 + lq * 8];
                    tmp[0][nt2] = mfma16(w2f[0][ks], hb, tmp[0][nt2]);
                    tmp[1][nt2] = mfma16(w2f[1][ks], hb, tmp[1][nt2]);
                }
            }
            __syncthreads();
        }
        float wtv[4];
        #pragma unroll
        for (int nt2 = 0; nt2 < 4; ++nt2)
            wtv[nt2] = (pass == 0) ? 1.0f : wls[(nt2 * 16 + lr) * 4 + (pass - 1)];
        #pragma unroll
        for (int t2 = 0; t2 < 2; ++t2) {
            const f32x4 b2v = *(const f32x4*)&b2[wave * 32 + t2 * 16 + lq * 4];
            #pragma unroll
            for (int nt2 = 0; nt2 < 4; ++nt2)
                #pragma unroll
                for (int r = 0; r < 4; ++r)
                    fin[t2][nt2][r] += wtv[nt2] * (tmp[t2][nt2][r] + b2v[r]);
        }
    }

    #pragma unroll
    for (int t2 = 0; t2 < 2; ++t2)
        #pragma unroll
        for (int nt2 = 0; nt2 < 4; ++nt2) {
            unsigned short* dst = outT + ((size_t)(base + nt2 * 16 + lr)) * 128
                                + wave * 32 + t2 * 16 + lq * 4;
            uint2 wv = {pk_bf16(fin[t2][nt2][0], fin[t2][nt2][1]),
                        pk_bf16(fin[t2][nt2][2], fin[t2][nt2][3])};
            *(uint2*)dst = wv;
        }
}

__device__ void final_tile_body(
    int blk, int tid,
    const float* __restrict__ x, const unsigned short* __restrict__ outT,
    const int* __restrict__ pixslot, unsigned short* ts,
    float* __restrict__ out)
{
    const int b = blk / 144;
    const int p0 = (blk - b * 144) * 64;
    {
        const int p = tid >> 2, q = tid & 3;
        const int slot = pixslot[blk * 64 + p];
        const unsigned short* src = outT + (size_t)slot * 128 + q * 32;
        unsigned short* dst = &ts[p * 133 + q * 32];
        #pragma unroll
        for (int j = 0; j < 4; ++j)
            *(u16x8*)(dst + j * 8) = *(const u16x8*)(src + j * 8);
    }
    __syncthreads();
    const int pl = tid & 63, cq = tid >> 6;
    const float* xb = x + (size_t)b * 128 * HWP + p0;
    float* ob = out + (size_t)b * 128 * HWP + p0;
    #pragma unroll
    for (int c0 = 0; c0 < 128; c0 += 4) {
        int c = c0 + cq;
        ob[(size_t)c * HWP + pl] = xb[(size_t)c * HWP + pl] + bf2f(ts[pl * 133 + c]);
    }
}

// ---------------- cooperative mega-kernel ----------------

__global__ __launch_bounds__(256, 2) void moe_mega(
    const float* __restrict__ x,   const float* __restrict__ gw,
    const float* __restrict__ gb,
    const float* __restrict__ sw1, const float* __restrict__ sb1,
    const float* __restrict__ sw2, const float* __restrict__ sb2,
    const float* __restrict__ ew1, const float* __restrict__ eb1,
    const float* __restrict__ ew2, const float* __restrict__ eb2,
    unsigned short* __restrict__ wbf, unsigned short* __restrict__ xT,
    unsigned short* __restrict__ outT,
    int* __restrict__ pixmask, float* __restrict__ pixw3,
    int* __restrict__ pixaux,  int* __restrict__ idx,
    int* __restrict__ tmask,   int* __restrict__ tbase,
    int* __restrict__ bincount, int* __restrict__ ntiles,
    float* __restrict__ accum, float* __restrict__ out)
{
    cg::grid_group grid = cg::this_grid();
    __shared__ __align__(16) char smem[36864];
    const int tid = threadIdx.x;

    // phase 0: weight convert + zero init
    {
        const int tidg = blockIdx.x * 256 + tid;
        const int nthr = NB * 256;
        for (int i = tidg; i < 1179648; i += nthr) {
            float v;
            if (i < 65536) v = sw1[i];
            else if (i < 131072) v = sw2[i - 65536];
            else if (i < 655360) v = ew1[i - 131072];
            else v = ew2[i - 655360];
            wbf[i] = f2bf(v);
        }
        for (int s = tidg; s < MAXSLOTS; s += nthr) idx[s] = 0;
        if (tidg < 256) bincount[tidg] = 0;
        if (tidg < 16) accum[tidg] = 0.f;
    }
    grid.sync();

    // phase 1: router + xT
    {
        float* gws = (float*)smem;
        unsigned short* xls = (unsigned short*)(smem + 4096);
        float* part = (float*)(smem + 4096 + 16896);
        for (int i = tid; i < 1024; i += 256) gws[i] = gw[i];
        __syncthreads();
        for (int blk = blockIdx.x; blk < 1152; blk += NB) {
            router_body(blk, tid, x, gb, gws, xls, part,
                        xT, pixmask, pixw3, pixaux, bincount, accum);
            __syncthreads();
        }
    }
    grid.sync();

    // phase 2: scan + fill
    {
        int* spc = (int*)smem;
        int* snt = (int*)(smem + 1024);
        int* bbv = (int*)(smem + 2048);
        const int c = bincount[tid];
        const int nt = (c + 63) >> 6;
        const int pc = nt << 6;
        spc[tid] = pc; snt[tid] = nt;
        __syncthreads();
        #pragma unroll
        for (int off = 1; off < 256; off <<= 1) {
            int a = (tid >= off) ? spc[tid - off] : 0;
            int d = (tid >= off) ? snt[tid - off] : 0;
            __syncthreads();
            spc[tid] += a; snt[tid] += d;
            __syncthreads();
        }
        const int base = spc[tid] - pc;
        const int tstart = snt[tid] - nt;
        bbv[tid] = base;
        if (blockIdx.x == 0) {
            for (int j = 0; j < nt; ++j) {
                tmask[tstart + j] = tid;
                tbase[tstart + j] = base + (j << 6);
            }
            if (tid == 255) ntiles[0] = snt[255];
        }
        __syncthreads();
        for (int g0 = blockIdx.x * 256; g0 < NPIX; g0 += NB * 256) {
            int gp = g0 + tid;
            int mask = pixmask[gp];
            int slot = bbv[mask] + pixaux[gp];
            idx[slot] = gp;
            pixaux[gp] = slot;
        }
    }
    grid.sync();

    // phase 3: sparse MoE
    {
        unsigned short* xs = (unsigned short*)smem;
        unsigned short* hs = (unsigned short*)(smem + 17408);
        float* wls = (float*)(smem + 34816);
        const int NT = ntiles[0];
        for (int t = blockIdx.x; t < NT; t += NB) {
            moe_tile_body(tmask[t], tbase[t], tid, xT, idx, pixw3,
                          wbf, sb1, sb2, eb1, eb2, xs, hs, wls, outT);
            __syncthreads();
        }
    }
    grid.sync();

    // phase 4: final add + aux loss
    {
        if (blockIdx.x == 0 && tid == 0) {
            float aux = 0.f;
            #pragma unroll
            for (int e = 0; e < 8; ++e) aux += accum[e] * accum[8 + e];
            out[9437184] = 8.0f * aux / ((float)NPIX * (float)NPIX);
        }
        unsigned short* ts = (unsigned short*)smem;
        for (int blk = blockIdx.x; blk < 1152; blk += NB) {
            final_tile_body(blk, tid, x, outT, pixaux, ts, out);
            __syncthreads();
        }
    }
}

// ---------------- r7 fallback kernels ----------------

__global__ __launch_bounds__(256) void router_mk(
    const float* __restrict__ x, const float* __restrict__ gw,
    const float* __restrict__ gb,
    const float* __restrict__ sw1, const float* __restrict__ sw2,
    const float* __restrict__ ew1, const float* __restrict__ ew2,
    unsigned short* __restrict__ wbf, unsigned short* __restrict__ xT,
    int* __restrict__ pixmask, float* __restrict__ pixw3,
    int* __restrict__ pixaux, int* __restrict__ bincount,
    float* __restrict__ accum)
{
    __shared__ float gws[1024];
    __shared__ unsigned short xls[64 * 132];
    __shared__ float part[4 * 64 * 8];
    const int tid = threadIdx.x;
    const int blk = blockIdx.x;
    {
        int i = blk * 256 + tid;
        #pragma unroll
        for (int j = 0; j < 4; ++j) {
            float v;
            if (i < 65536) v = sw1[i];
            else if (i < 131072) v = sw2[i - 65536];
            else if (i < 655360) v = ew1[i - 131072];
            else v = ew2[i - 655360];
            wbf[i] = f2bf(v);
            i += 1152 * 256;
        }
    }
    for (int i = tid; i < 1024; i += 256) gws[i] = gw[i];
    __syncthreads();
    router_body(blk, tid, x, gb, gws, xls, part,
                xT, pixmask, pixw3, pixaux, bincount, accum);
}

__global__ __launch_bounds__(256) void fill_mk(
    const int* __restrict__ bincount, const int* __restrict__ pixmask,
    int* __restrict__ idx, int* __restrict__ pixaux,
    int* __restrict__ tmask, int* __restrict__ tbase, int* __restrict__ ntiles)
{
    __shared__ int spc[256], snt[256], bbv[256];
    const int tid = threadIdx.x;
    const int c = bincount[tid];
    const int nt = (c + 63) >> 6;
    const int pc = nt << 6;
    spc[tid] = pc; snt[tid] = nt;
    __syncthreads();
    #pragma unroll
    for (int off = 1; off < 256; off <<= 1) {
        int a = (tid >= off) ? spc[tid - off] : 0;
        int d = (tid >= off) ? snt[tid - off] : 0;
        __syncthreads();
        spc[tid] += a; snt[tid] += d;
        __syncthreads();
    }
    const int base = spc[tid] - pc;
    const int tstart = snt[tid] - nt;
    bbv[tid] = base;
    if (blockIdx.x == 0) {
        for (int j = 0; j < nt; ++j) {
            tmask[tstart + j] = tid;
            tbase[tstart + j] = base + (j << 6);
        }
        if (tid == 255) ntiles[0] = snt[255];
    }
    __syncthreads();
    const int gp = blockIdx.x * 256 + tid;
    int mask = pixmask[gp];
    int slot = bbv[mask] + pixaux[gp];
    idx[slot] = gp;
    pixaux[gp] = slot;
}

__global__ __launch_bounds__(256, 3) void moe_mk(
    const unsigned short* __restrict__ xT, const int* __restrict__ idx,
    const float* __restrict__ pixw3,
    const int* __restrict__ tmask, const int* __restrict__ tbase,
    const int* __restrict__ ntiles,
    const unsigned short* __restrict__ wbf,
    const float* __restrict__ sb1, const float* __restrict__ sb2,
    const float* __restrict__ eb1, const float* __restrict__ eb2,
    unsigned short* __restrict__ outT)
{
    __shared__ unsigned short xs[64 * LDX];
    __shared__ unsigned short hs[64 * LDH];
    __shared__ float wls[64 * 4];
    const int t = blockIdx.x;
    if (t >= ntiles[0]) return;
    moe_tile_body(tmask[t], tbase[t], threadIdx.x, xT, idx, pixw3,
                  wbf, sb1, sb2, eb1, eb2, xs, hs, wls, outT);
}

__global__ __launch_bounds__(256) void final_mk(
    const float* __restrict__ x, const unsigned short* __restrict__ outT,
    const int* __restrict__ pixslot, const float* __restrict__ accum,
    float* __restrict__ out)
{
    if (blockIdx.x == 0 && threadIdx.x == 0) {
        float aux = 0.f;
        #pragma unroll
        for (int e = 0; e < 8; ++e) aux += accum[e] * accum[8 + e];
        out[9437184] = 8.0f * aux / ((float)NPIX * (float)NPIX);
    }
    __shared__ unsigned short ts[64 * 133];
    final_tile_body(blockIdx.x, threadIdx.x, x, outT, pixslot, ts, out);
}

// ---------------- launch ----------------

extern "C" void kernel_launch(void* const* d_in, const int* in_sizes, int n_in,
                              void* d_out, int out_size, void* d_ws, size_t ws_size,
                              hipStream_t stream)
{
    const float* x   = (const float*)d_in[0];
    const float* sw1 = (const float*)d_in[1];
    const float* sb1 = (const float*)d_in[2];
    const float* sw2 = (const float*)d_in[3];
    const float* sb2 = (const float*)d_in[4];
    const float* gw  = (const float*)d_in[5];
    const float* gb  = (const float*)d_in[6];
    const float* ew1 = (const float*)d_in[7];
    const float* eb1 = (const float*)d_in[8];
    const float* ew2 = (const float*)d_in[9];
    const float* eb2 = (const float*)d_in[10];
    float* out = (float*)d_out;
    char* ws = (char*)d_ws;

    const size_t o_wbf     = 0;
    const size_t o_xT      = 2359296;
    const size_t o_outT    = o_xT + 18874368;
    const size_t o_pixmask = o_outT + 19791872;
    const size_t o_pixw3   = o_pixmask + 294912;
    const size_t o_pixaux  = o_pixw3 + 884736;
    const size_t o_tmask   = o_pixaux + 294912;
    const size_t o_tbase   = o_tmask + 4864;
    const size_t o_idx     = o_tbase + 4864;
    const size_t o_cnt     = o_idx + 309248;
    const size_t o_ntiles  = o_cnt + 1024;
    const size_t o_accum   = o_ntiles + 16;
    const size_t MEMSET_SZ = 309248 + 1024 + 16 + 64;

    unsigned short* wbf  = (unsigned short*)(ws + o_wbf);
    unsigned short* xT   = (unsigned short*)(ws + o_xT);
    unsigned short* outT = (unsigned short*)(ws + o_outT);
    int* pixmask  = (int*)(ws + o_pixmask);
    float* pixw3  = (float*)(ws + o_pixw3);
    int* pixaux   = (int*)(ws + o_pixaux);
    int* tmask    = (int*)(ws + o_tmask);
    int* tbase    = (int*)(ws + o_tbase);
    int* idx      = (int*)(ws + o_idx);
    int* bincount = (int*)(ws + o_cnt);
    int* ntiles   = (int*)(ws + o_ntiles);
    float* accum  = (float*)(ws + o_accum);

    void* kargs[] = {
        (void*)&x, (void*)&gw, (void*)&gb,
        (void*)&sw1, (void*)&sb1, (void*)&sw2, (void*)&sb2,
        (void*)&ew1, (void*)&eb1, (void*)&ew2, (void*)&eb2,
        (void*)&wbf, (void*)&xT, (void*)&outT,
        (void*)&pixmask, (void*)&pixw3, (void*)&pixaux, (void*)&idx,
        (void*)&tmask, (void*)&tbase, (void*)&bincount, (void*)&ntiles,
        (void*)&accum, (void*)&out
    };
    hipError_t err = hipLaunchCooperativeKernel((const void*)moe_mega, dim3(NB),
                                                dim3(256), kargs, 0, stream);
    if (err != hipSuccess) {
        // fallback: proven r7 multi-kernel chain
        (void)hipMemsetAsync(ws + o_idx, 0, MEMSET_SZ, stream);
        router_mk<<<1152, 256, 0, stream>>>(x, gw, gb, sw1, sw2, ew1, ew2, wbf,
                                            xT, pixmask, pixw3, pixaux, bincount, accum);
        fill_mk<<<288, 256, 0, stream>>>(bincount, pixmask, idx, pixaux,
                                         tmask, tbase, ntiles);
        moe_mk<<<MAXTILES, 256, 0, stream>>>(xT, idx, pixw3, tmask, tbase, ntiles,
                                             wbf, sb1, sb2, eb1, eb2, outT);
        final_mk<<<1152, 256, 0, stream>>>(x, outT, pixaux, accum, out);
    }
}

// Round 11
// 574.900 us; speedup vs baseline: 1.3915x; 1.3915x over previous
//
#include <hip/hip_runtime.h>

// SharedSparseMoEBlock on gfx950 — round 11: r7 chain + (a) moe hs-dbuf
// (no weight hoist — r8 proved hoist spills), (b) moe split into 3 tile-range
// dispatches to surface the largest aux kernel in the rocprof top-5.

typedef __bf16 bf16x8 __attribute__((ext_vector_type(8)));
typedef unsigned short u16x8 __attribute__((ext_vector_type(8)));
typedef float f32x4 __attribute__((ext_vector_type(4)));

#define HWP 9216
#define NPIX 73728
#define LDX 136
#define LDH 136
#define MAXSLOTS 77312
#define MAXTILES 1208
#define TSPLIT 403     // ceil(1208/3)

__device__ __forceinline__ unsigned short f2bf(float f) {
    unsigned u = __float_as_uint(f);
    u += 0x7fffu + ((u >> 16) & 1u);   // RNE
    return (unsigned short)(u >> 16);
}

__device__ __forceinline__ unsigned pk_bf16(float a, float b) {
    return (unsigned)f2bf(a) | ((unsigned)f2bf(b) << 16);
}

__device__ __forceinline__ float bf2f(unsigned short h) {
    return __uint_as_float((unsigned)h << 16);
}

__device__ __forceinline__ float fast_gelu(float x) {
    float x2 = x * x;
    float u = x * fmaf(0.0356774081f, x2, 0.7978845608f);
    float e = __builtin_amdgcn_exp2f(u * 2.8853900818f);
    float r = __builtin_amdgcn_rcpf(e + 1.0f);
    float t = fmaf(-2.0f, r, 1.0f);
    float s = 0.5f * x;
    return fmaf(s, t, s);
}

__device__ __forceinline__ f32x4 mfma16(u16x8 a, u16x8 b, f32x4 c) {
    return __builtin_amdgcn_mfma_f32_16x16x32_bf16(
        __builtin_bit_cast(bf16x8, a), __builtin_bit_cast(bf16x8, b), c, 0, 0, 0);
}

// router + weight convert + xT write (r7-identical)
__global__ __launch_bounds__(256) void router_fused(
    const float* __restrict__ x, const float* __restrict__ gw,
    const float* __restrict__ gb,
    const float* __restrict__ sw1, const float* __restrict__ sw2,
    const float* __restrict__ ew1, const float* __restrict__ ew2,
    unsigned short* __restrict__ wbf,
    unsigned short* __restrict__ xT,
    int* __restrict__ pixmask, float* __restrict__ pixw3,
    int* __restrict__ pixaux,
    int* __restrict__ bincount, float* __restrict__ accum)
{
    __shared__ float gws[8 * 128];
    __shared__ unsigned short xls[64 * 132];
    __shared__ float part[4 * 64 * 8];

    const int tid = threadIdx.x;
    const int blk = blockIdx.x;               // grid = 1152

    {   // weight conversion: 4 elems/thread
        int i = blk * 256 + tid;
        #pragma unroll
        for (int j = 0; j < 4; ++j) {
            float v;
            if (i < 65536) v = sw1[i];
            else if (i < 131072) v = sw2[i - 65536];
            else if (i < 655360) v = ew1[i - 131072];
            else v = ew2[i - 655360];
            wbf[i] = f2bf(v);
            i += 1152 * 256;
        }
    }

    for (int i = tid; i < 1024; i += 256) gws[i] = gw[i];
    __syncthreads();

    const int b = blk / 144;
    const int p0 = (blk - b * 144) * 64;
    const int p = tid & 63, q = tid >> 6;
    const float* xb = x + (size_t)b * 128 * HWP + p0 + p;

    float lg[8];
    #pragma unroll
    for (int e = 0; e < 8; ++e) lg[e] = 0.f;
    #pragma unroll
    for (int k = 0; k < 32; ++k) {
        int c = q * 32 + k;
        float xv = xb[(size_t)c * HWP];
        xls[p * 132 + c] = f2bf(xv);
        #pragma unroll
        for (int e = 0; e < 8; ++e) lg[e] = fmaf(xv, gws[e * 128 + c], lg[e]);
    }
    #pragma unroll
    for (int e = 0; e < 8; ++e) part[(q * 64 + p) * 8 + e] = lg[e];
    __syncthreads();

    if (tid < 64) {
        const int gp = b * HWP + p0 + tid;
        float l2[8];
        #pragma unroll
        for (int e = 0; e < 8; ++e)
            l2[e] = gb[e] + part[tid * 8 + e] + part[(64 + tid) * 8 + e]
                  + part[(128 + tid) * 8 + e] + part[(192 + tid) * 8 + e];
        float mx = l2[0];
        #pragma unroll
        for (int e = 1; e < 8; ++e) mx = fmaxf(mx, l2[e]);
        float pr[8]; float s = 0.f;
        #pragma unroll
        for (int e = 0; e < 8; ++e) { pr[e] = __expf(l2[e] - mx); s += pr[e]; }
        float sinv = __builtin_amdgcn_rcpf(s);
        #pragma unroll
        for (int e = 0; e < 8; ++e) pr[e] *= sinv;

        unsigned chosen = 0; float topsum = 0.f;
        for (int k = 0; k < 3; ++k) {
            int best = 0; float bv = -1.f;
            #pragma unroll
            for (int e = 0; e < 8; ++e) {
                bool ok = !((chosen >> e) & 1u) && pr[e] > bv;
                bv = ok ? pr[e] : bv;
                best = ok ? e : best;
            }
            chosen |= 1u << best;
            topsum += bv;
        }
        float tinv = __builtin_amdgcn_rcpf(topsum);

        pixmask[gp] = (int)chosen;
        {
            int j = 0;
            #pragma unroll
            for (int e = 0; e < 8; ++e)
                if ((chosen >> e) & 1u) { pixw3[gp * 3 + j] = pr[e] * tinv; ++j; }
        }

        unsigned long long eq = ~0ull;
        #pragma unroll
        for (int bit = 0; bit < 8; ++bit) {
            unsigned long long bb = __ballot((chosen >> bit) & 1u);
            eq &= ((chosen >> bit) & 1u) ? bb : ~bb;
        }
        const unsigned long long lowmask = (tid == 0) ? 0ull : (~0ull >> (64 - tid));
        int rank = __popcll(eq & lowmask);
        int cnt = __popcll(eq);
        int leader = __ffsll((unsigned long long)eq) - 1;
        int off_val = 0;
        if (rank == 0) off_val = atomicAdd(&bincount[chosen], cnt);
        int binoff = __shfl(off_val, leader);
        pixaux[gp] = binoff + rank;

        #pragma unroll
        for (int e = 0; e < 8; ++e) {
            float v = pr[e];
            float c2 = ((chosen >> e) & 1u) ? 1.f : 0.f;
            #pragma unroll
            for (int off = 32; off > 0; off >>= 1) {
                v += __shfl_down(v, off);
                c2 += __shfl_down(c2, off);
            }
            if (tid == 0) {
                atomicAdd(&accum[e], v);
                atomicAdd(&accum[8 + e], c2);
            }
        }
    }

    {
        const int pp = tid >> 2, qq = tid & 3;
        unsigned short* dst = xT + ((size_t)blk * 64 + pp) * 128 + qq * 32;
        const unsigned short* src = &xls[pp * 132 + qq * 32];
        #pragma unroll
        for (int j = 0; j < 4; ++j)
            *(u16x8*)(dst + j * 8) = *(const u16x8*)(src + j * 8);
    }
}

__global__ __launch_bounds__(256) void fill_bins(
    const int* __restrict__ bincount, const int* __restrict__ pixmask,
    int* __restrict__ idx, int* __restrict__ pixaux,
    int* __restrict__ tileMask, int* __restrict__ tileBase,
    int* __restrict__ ntiles)
{
    __shared__ int spc[256], snt[256], bb[256];
    const int tid = threadIdx.x;
    const int c = bincount[tid];
    const int nt = (c + 63) >> 6;
    const int pc = nt << 6;
    spc[tid] = pc; snt[tid] = nt;
    __syncthreads();
    #pragma unroll
    for (int off = 1; off < 256; off <<= 1) {
        int a = (tid >= off) ? spc[tid - off] : 0;
        int d = (tid >= off) ? snt[tid - off] : 0;
        __syncthreads();
        spc[tid] += a; snt[tid] += d;
        __syncthreads();
    }
    const int base = spc[tid] - pc;
    bb[tid] = base;
    if (blockIdx.x == 0) {
        const int tstart = snt[tid] - nt;
        for (int j = 0; j < nt; ++j) {
            tileMask[tstart + j] = tid;
            tileBase[tstart + j] = base + (j << 6);
        }
        if (tid == 255) ntiles[0] = snt[255];
    }
    __syncthreads();

    const int gp = blockIdx.x * 256 + tid;
    int mask = pixmask[gp];
    int slot = bb[mask] + pixaux[gp];
    idx[slot] = gp;
    pixaux[gp] = slot;
}

// moe: r7 structure + hs double-buffer (1 barrier/chunk), NO weight hoist.
// toff = tile-range offset (kernel split into 3 dispatches for profiling).
__global__ __launch_bounds__(256, 3) void moe_sparse(
    int toff,
    const unsigned short* __restrict__ xT, const int* __restrict__ idx,
    const float* __restrict__ pixw3,
    const int* __restrict__ tileMask, const int* __restrict__ tileBase,
    const int* __restrict__ ntiles,
    const unsigned short* __restrict__ wbf,
    const float* __restrict__ sb1, const float* __restrict__ sb2,
    const float* __restrict__ eb1, const float* __restrict__ eb2,
    unsigned short* __restrict__ outT)
{
    __shared__ unsigned short xs[64 * LDX];
    __shared__ unsigned short hs[2][64 * LDH];
    __shared__ float wls[64 * 4];

    const int t = toff + blockIdx.x;
    if (t >= ntiles[0]) return;
    const int mask = tileMask[t];
    const int base = tileBase[t];
    const int tid = threadIdx.x;

    {
        const int p = tid >> 2, q = tid & 3;
        const int gp = idx[base + p];
        const unsigned short* src = xT + (size_t)gp * 128 + q * 32;
        unsigned short* dst = &xs[p * LDX + q * 32];
        #pragma unroll
        for (int j = 0; j < 4; ++j)
            *(u16x8*)(dst + j * 8) = *(const u16x8*)(src + j * 8);
        if (q == 0) {
            wls[p * 4 + 0] = pixw3[gp * 3 + 0];
            wls[p * 4 + 1] = pixw3[gp * 3 + 1];
            wls[p * 4 + 2] = pixw3[gp * 3 + 2];
        }
    }
    __syncthreads();

    int el[3];
    { int n = 0;
      #pragma unroll
      for (int e = 0; e < 8; ++e) if ((mask >> e) & 1) { if (n < 3) el[n] = e; ++n; } }

    const int wave = tid >> 6;
    const int lr = tid & 15;
    const int lq = (tid >> 4) & 3;

    const f32x4 vzero = {0.f, 0.f, 0.f, 0.f};
    f32x4 fin[2][4];
    #pragma unroll
    for (int t2 = 0; t2 < 2; ++t2)
        #pragma unroll
        for (int nt2 = 0; nt2 < 4; ++nt2) fin[t2][nt2] = vzero;

    for (int pass = 0; pass < 4; ++pass) {
        const unsigned short* w1; const unsigned short* w2;
        const float* b1; const float* b2;
        if (pass == 0) { w1 = wbf; b1 = sb1; w2 = wbf + 65536; b2 = sb2; }
        else {
            int e = el[pass - 1];
            w1 = wbf + 131072 + (size_t)e * (512 * 128);  b1 = eb1 + e * 512;
            w2 = wbf + 655360 + (size_t)e * (128 * 512);  b2 = eb2 + e * 128;
        }

        f32x4 tmp[2][4];
        #pragma unroll
        for (int t2 = 0; t2 < 2; ++t2)
            #pragma unroll
            for (int nt2 = 0; nt2 < 4; ++nt2) tmp[t2][nt2] = vzero;

        for (int chunk = 0; chunk < 4; ++chunk) {
            unsigned short* hsb = hs[(pass * 4 + chunk) & 1];

            // GEMM1: load w1 frags just-in-time (no long liveness)
            u16x8 w1f[2][4];
            #pragma unroll
            for (int t2 = 0; t2 < 2; ++t2) {
                const int hid0 = chunk * 128 + wave * 32 + t2 * 16;
                const u16x8* wr = (const u16x8*)(w1 + (size_t)(hid0 + lr) * 128) + lq;
                #pragma unroll
                for (int ks = 0; ks < 4; ++ks) w1f[t2][ks] = wr[ks * 4];
            }
            f32x4 acc[2][4];
            #pragma unroll
            for (int t2 = 0; t2 < 2; ++t2)
                #pragma unroll
                for (int nt2 = 0; nt2 < 4; ++nt2) acc[t2][nt2] = vzero;
            #pragma unroll
            for (int ks = 0; ks < 4; ++ks) {
                #pragma unroll
                for (int nt2 = 0; nt2 < 4; ++nt2) {
                    u16x8 xf = *(const u16x8*)&xs[(nt2 * 16 + lr) * LDX + ks * 32 + lq * 8];
                    acc[0][nt2] = mfma16(w1f[0][ks], xf, acc[0][nt2]);
                    acc[1][nt2] = mfma16(w1f[1][ks], xf, acc[1][nt2]);
                }
            }
            #pragma unroll
            for (int t2 = 0; t2 < 2; ++t2) {
                const int hl = wave * 32 + t2 * 16 + lq * 4;
                const f32x4 b1v = *(const f32x4*)&b1[chunk * 128 + hl];
                #pragma unroll
                for (int nt2 = 0; nt2 < 4; ++nt2) {
                    float g0 = fast_gelu(acc[t2][nt2][0] + b1v[0]);
                    float g1 = fast_gelu(acc[t2][nt2][1] + b1v[1]);
                    float g2 = fast_gelu(acc[t2][nt2][2] + b1v[2]);
                    float g3 = fast_gelu(acc[t2][nt2][3] + b1v[3]);
                    uint2 wv = {pk_bf16(g0, g1), pk_bf16(g2, g3)};
                    *(uint2*)&hsb[(nt2 * 16 + lr) * LDH + hl] = wv;
                }
            }
            __syncthreads();   // single barrier per chunk (dbuf removes the 2nd)
            // GEMM2: w2 frags loaded here (post-barrier, r7-style — no hoist)
            u16x8 w2f[2][4];
            #pragma unroll
            for (int t2 = 0; t2 < 2; ++t2) {
                const int c0 = wave * 32 + t2 * 16;
                const u16x8* wr = (const u16x8*)(w2 + (size_t)(c0 + lr) * 512 + chunk * 128) + lq;
                #pragma unroll
                for (int ks = 0; ks < 4; ++ks) w2f[t2][ks] = wr[ks * 4];
            }
            #pragma unroll
            for (int ks = 0; ks < 4; ++ks) {
                #pragma unroll
                for (int nt2 = 0; nt2 < 4; ++nt2) {
                    u16x8 hb = *(const u16x8*)&hsb[(nt2 * 16 + lr) * LDH + ks * 32 + lq * 8];
                    tmp[0][nt2] = mfma16(w2f[0][ks], hb, tmp[0][nt2]);
                    tmp[1][nt2] = mfma16(w2f[1][ks], hb, tmp[1][nt2]);
                }
            }
            // no trailing barrier: next chunk writes the other hs buffer
        }
        float wtv[4];
        #pragma unroll
        for (int nt2 = 0; nt2 < 4; ++nt2)
            wtv[nt2] = (pass == 0) ? 1.0f : wls[(nt2 * 16 + lr) * 4 + (pass - 1)];
        #pragma unroll
        for (int t2 = 0; t2 < 2; ++t2) {
            const f32x4 b2v = *(const f32x4*)&b2[wave * 32 + t2 * 16 + lq * 4];
            #pragma unroll
            for (int nt2 = 0; nt2 < 4; ++nt2)
                #pragma unroll
                for (int r = 0; r < 4; ++r)
                    fin[t2][nt2][r] += wtv[nt2] * (tmp[t2][nt2][r] + b2v[r]);
        }
    }

    #pragma unroll
    for (int t2 = 0; t2 < 2; ++t2)
        #pragma unroll
        for (int nt2 = 0; nt2 < 4; ++nt2) {
            unsigned short* dst = outT + ((size_t)(base + nt2 * 16 + lr)) * 128
                                + wave * 32 + t2 * 16 + lq * 4;
            uint2 wv = {pk_bf16(fin[t2][nt2][0], fin[t2][nt2][1]),
                        pk_bf16(fin[t2][nt2][2], fin[t2][nt2][3])};
            *(uint2*)dst = wv;
        }
}

__global__ __launch_bounds__(256) void final_add(
    const float* __restrict__ x, const unsigned short* __restrict__ outT,
    const int* __restrict__ pixslot, const float* __restrict__ accum,
    float* __restrict__ out)
{
    if (blockIdx.x == 0 && threadIdx.x == 0) {
        float aux = 0.f;
        #pragma unroll
        for (int e = 0; e < 8; ++e) aux += accum[e] * accum[8 + e];
        out[9437184] = 8.0f * aux / ((float)NPIX * (float)NPIX);
    }
    __shared__ unsigned short ts[64 * 133];
    const int blk = blockIdx.x;
    const int b = blk / 144;
    const int p0 = (blk - b * 144) * 64;
    const int tid = threadIdx.x;
    {
        const int p = tid >> 2, q = tid & 3;
        const int slot = pixslot[blk * 64 + p];
        const unsigned short* src = outT + (size_t)slot * 128 + q * 32;
        unsigned short* dst = &ts[p * 133 + q * 32];
        #pragma unroll
        for (int j = 0; j < 4; ++j)
            *(u16x8*)(dst + j * 8) = *(const u16x8*)(src + j * 8);
    }
    __syncthreads();
    const int pl = tid & 63, cq = tid >> 6;
    const float* xb = x + (size_t)b * 128 * HWP + p0;
    float* ob = out + (size_t)b * 128 * HWP + p0;
    #pragma unroll
    for (int c0 = 0; c0 < 128; c0 += 4) {
        int c = c0 + cq;
        ob[(size_t)c * HWP + pl] = xb[(size_t)c * HWP + pl] + bf2f(ts[pl * 133 + c]);
    }
}

extern "C" void kernel_launch(void* const* d_in, const int* in_sizes, int n_in,
                              void* d_out, int out_size, void* d_ws, size_t ws_size,
                              hipStream_t stream)
{
    const float* x   = (const float*)d_in[0];
    const float* sw1 = (const float*)d_in[1];
    const float* sb1 = (const float*)d_in[2];
    const float* sw2 = (const float*)d_in[3];
    const float* sb2 = (const float*)d_in[4];
    const float* gw  = (const float*)d_in[5];
    const float* gb  = (const float*)d_in[6];
    const float* ew1 = (const float*)d_in[7];
    const float* eb1 = (const float*)d_in[8];
    const float* ew2 = (const float*)d_in[9];
    const float* eb2 = (const float*)d_in[10];
    float* out = (float*)d_out;
    char* ws = (char*)d_ws;

    const size_t o_wbf     = 0;
    const size_t o_xT      = 2359296;
    const size_t o_outT    = o_xT + 18874368;
    const size_t o_pixmask = o_outT + 19791872;
    const size_t o_pixw3   = o_pixmask + 294912;
    const size_t o_pixaux  = o_pixw3 + 884736;
    const size_t o_tmask   = o_pixaux + 294912;
    const size_t o_tbase   = o_tmask + 4864;
    const size_t o_idx     = o_tbase + 4864;
    const size_t o_cnt     = o_idx + 309248;
    const size_t o_ntiles  = o_cnt + 1024;
    const size_t o_accum   = o_ntiles + 16;
    const size_t MEMSET_SZ = 309248 + 1024 + 16 + 64;

    unsigned short* wbf  = (unsigned short*)(ws + o_wbf);
    unsigned short* xT   = (unsigned short*)(ws + o_xT);
    unsigned short* outT = (unsigned short*)(ws + o_outT);
    int* pixmask  = (int*)(ws + o_pixmask);
    float* pixw3  = (float*)(ws + o_pixw3);
    int* pixaux   = (int*)(ws + o_pixaux);
    int* tmask    = (int*)(ws + o_tmask);
    int* tbase    = (int*)(ws + o_tbase);
    int* idx      = (int*)(ws + o_idx);
    int* bincount = (int*)(ws + o_cnt);
    int* ntiles   = (int*)(ws + o_ntiles);
    float* accum  = (float*)(ws + o_accum);

    (void)hipMemsetAsync(ws + o_idx, 0, MEMSET_SZ, stream);
    router_fused<<<1152, 256, 0, stream>>>(x, gw, gb, sw1, sw2, ew1, ew2, wbf,
                                           xT, pixmask, pixw3, pixaux, bincount, accum);
    fill_bins<<<288, 256, 0, stream>>>(bincount, pixmask, idx, pixaux,
                                       tmask, tbase, ntiles);
    moe_sparse<<<TSPLIT, 256, 0, stream>>>(0, xT, idx, pixw3, tmask, tbase, ntiles,
        wbf, sb1, sb2, eb1, eb2, outT);
    moe_sparse<<<TSPLIT, 256, 0, stream>>>(TSPLIT, xT, idx, pixw3, tmask, tbase, ntiles,
        wbf, sb1, sb2, eb1, eb2, outT);
    moe_sparse<<<MAXTILES - 2 * TSPLIT, 256, 0, stream>>>(2 * TSPLIT, xT, idx, pixw3,
        tmask, tbase, ntiles, wbf, sb1, sb2, eb1, eb2, outT);
    final_add<<<1152, 256, 0, stream>>>(x, outT, pixaux, accum, out);
}

// Round 12
// 337.528 us; speedup vs baseline: 2.3701x; 1.7033x over previous
//
#include <hip/hip_runtime.h>

// SharedSparseMoEBlock on gfx950 — round 12: fix router latency serialization.
// r11 found router_fused = 200us @ 2.8% VALU (serialized scalar strided loads).
// r12: (a) staging via 8x f32x4 coalesced loads/thread -> LDS f32 [c][p] tile,
// logits read LDS; (b) 16-way shadow atomics for bincount/accum; (c) moe_sparse
// reverted to exact r7 single-dispatch form to isolate the delta.

typedef __bf16 bf16x8 __attribute__((ext_vector_type(8)));
typedef unsigned short u16x8 __attribute__((ext_vector_type(8)));
typedef float f32x4 __attribute__((ext_vector_type(4)));

#define HWP 9216
#define NPIX 73728
#define LDX 136
#define LDH 136
#define LXP 68         // xls f32 pitch (17 banks: conflict-benign, 16B-aligned)
#define MAXSLOTS 77312
#define MAXTILES 1208
#define NSH 16         // atomic shadow copies

__device__ __forceinline__ unsigned short f2bf(float f) {
    unsigned u = __float_as_uint(f);
    u += 0x7fffu + ((u >> 16) & 1u);   // RNE
    return (unsigned short)(u >> 16);
}

__device__ __forceinline__ unsigned pk_bf16(float a, float b) {
    return (unsigned)f2bf(a) | ((unsigned)f2bf(b) << 16);
}

__device__ __forceinline__ float bf2f(unsigned short h) {
    return __uint_as_float((unsigned)h << 16);
}

__device__ __forceinline__ float fast_gelu(float x) {
    float x2 = x * x;
    float u = x * fmaf(0.0356774081f, x2, 0.7978845608f);
    float e = __builtin_amdgcn_exp2f(u * 2.8853900818f);
    float r = __builtin_amdgcn_rcpf(e + 1.0f);
    float t = fmaf(-2.0f, r, 1.0f);
    float s = 0.5f * x;
    return fmaf(s, t, s);
}

__device__ __forceinline__ f32x4 mfma16(u16x8 a, u16x8 b, f32x4 c) {
    return __builtin_amdgcn_mfma_f32_16x16x32_bf16(
        __builtin_bit_cast(bf16x8, a), __builtin_bit_cast(bf16x8, b), c, 0, 0, 0);
}

// router + weight convert + xT write. Staging via wide coalesced loads.
__global__ __launch_bounds__(256) void router_fused(
    const float* __restrict__ x, const float* __restrict__ gw,
    const float* __restrict__ gb,
    const float* __restrict__ sw1, const float* __restrict__ sw2,
    const float* __restrict__ ew1, const float* __restrict__ ew2,
    unsigned short* __restrict__ wbf,
    unsigned short* __restrict__ xT,
    int* __restrict__ pixmask, float* __restrict__ pixw3,
    int* __restrict__ pixaux,
    int* __restrict__ bincount, float* __restrict__ accum)
{
    __shared__ float gws[1024];
    __shared__ float xls[128 * LXP];          // f32 [channel][pixel]
    __shared__ float part[4 * 64 * 8];

    const int tid = threadIdx.x;
    const int blk = blockIdx.x;               // grid = 1152
    const int shadow = blk & (NSH - 1);

    {   // weight conversion: 4 elems/thread
        int i = blk * 256 + tid;
        #pragma unroll
        for (int j = 0; j < 4; ++j) {
            float v;
            if (i < 65536) v = sw1[i];
            else if (i < 131072) v = sw2[i - 65536];
            else if (i < 655360) v = ew1[i - 131072];
            else v = ew2[i - 655360];
            wbf[i] = f2bf(v);
            i += 1152 * 256;
        }
    }

    for (int i = tid; i < 1024; i += 256) gws[i] = gw[i];

    const int b = blk / 144;
    const int p0 = (blk - b * 144) * 64;
    const float* xb = x + (size_t)b * 128 * HWP + p0;

    // stage x: 8 independent f32x4 loads/thread, coalesced per wave
    #pragma unroll
    for (int j = 0; j < 8; ++j) {
        int id4 = j * 256 + tid;              // 2048 vec4 slots = 128c x 16g
        int c = id4 >> 4;
        int g = id4 & 15;
        f32x4 v = *(const f32x4*)(xb + (size_t)c * HWP + g * 4);
        *(f32x4*)&xls[c * LXP + g * 4] = v;
    }
    __syncthreads();

    // partial logits: wave q covers channels q*32..+31, lane p = pixel
    const int p = tid & 63, q = tid >> 6;
    {
        float lg[8];
        #pragma unroll
        for (int e = 0; e < 8; ++e) lg[e] = 0.f;
        #pragma unroll
        for (int k = 0; k < 32; ++k) {
            int c = q * 32 + k;
            float xv = xls[c * LXP + p];
            #pragma unroll
            for (int e = 0; e < 8; ++e) lg[e] = fmaf(xv, gws[e * 128 + c], lg[e]);
        }
        #pragma unroll
        for (int e = 0; e < 8; ++e) part[(q * 64 + p) * 8 + e] = lg[e];
    }
    __syncthreads();

    if (tid < 64) {                            // wave 0: one pixel per lane
        const int gp = b * HWP + p0 + tid;
        float l2[8];
        #pragma unroll
        for (int e = 0; e < 8; ++e)
            l2[e] = gb[e] + part[tid * 8 + e] + part[(64 + tid) * 8 + e]
                  + part[(128 + tid) * 8 + e] + part[(192 + tid) * 8 + e];
        float mx = l2[0];
        #pragma unroll
        for (int e = 1; e < 8; ++e) mx = fmaxf(mx, l2[e]);
        float pr[8]; float s = 0.f;
        #pragma unroll
        for (int e = 0; e < 8; ++e) { pr[e] = __expf(l2[e] - mx); s += pr[e]; }
        float sinv = __builtin_amdgcn_rcpf(s);
        #pragma unroll
        for (int e = 0; e < 8; ++e) pr[e] *= sinv;

        // top-3, first-index wins ties (matches lax.top_k)
        unsigned chosen = 0; float topsum = 0.f;
        for (int k = 0; k < 3; ++k) {
            int best = 0; float bv = -1.f;
            #pragma unroll
            for (int e = 0; e < 8; ++e) {
                bool ok = !((chosen >> e) & 1u) && pr[e] > bv;
                bv = ok ? pr[e] : bv;
                best = ok ? e : best;
            }
            chosen |= 1u << best;
            topsum += bv;
        }
        float tinv = __builtin_amdgcn_rcpf(topsum);

        pixmask[gp] = (int)chosen;
        {
            int j = 0;
            #pragma unroll
            for (int e = 0; e < 8; ++e)
                if ((chosen >> e) & 1u) { pixw3[gp * 3 + j] = pr[e] * tinv; ++j; }
        }

        // ballot equality-classes -> one shadowed atomic per class
        unsigned long long eq = ~0ull;
        #pragma unroll
        for (int bit = 0; bit < 8; ++bit) {
            unsigned long long bb = __ballot((chosen >> bit) & 1u);
            eq &= ((chosen >> bit) & 1u) ? bb : ~bb;
        }
        const unsigned long long lowmask = (tid == 0) ? 0ull : (~0ull >> (64 - tid));
        int rank = __popcll(eq & lowmask);
        int cnt = __popcll(eq);
        int leader = __ffsll((unsigned long long)eq) - 1;
        int off_val = 0;
        if (rank == 0) off_val = atomicAdd(&bincount[shadow * 256 + (int)chosen], cnt);
        int binoff = __shfl(off_val, leader);
        pixaux[gp] = binoff + rank;            // position within (shadow, bin)

        // aux: shuffle reduce, lane 0 -> 16 shadowed atomics
        #pragma unroll
        for (int e = 0; e < 8; ++e) {
            float v = pr[e];
            float c2 = ((chosen >> e) & 1u) ? 1.f : 0.f;
            #pragma unroll
            for (int off = 32; off > 0; off >>= 1) {
                v += __shfl_down(v, off);
                c2 += __shfl_down(c2, off);
            }
            if (tid == 0) {
                atomicAdd(&accum[shadow * 16 + e], v);
                atomicAdd(&accum[shadow * 16 + 8 + e], c2);
            }
        }
    }

    // xT write: pixel pp, channel quarter qq; xls read-only since staging barrier
    {
        const int pp = tid >> 2, qq = tid & 3;
        unsigned short* dst = xT + ((size_t)(blk * 64 + pp)) * 128 + qq * 32;
        #pragma unroll
        for (int j = 0; j < 4; ++j) {
            const int c0 = qq * 32 + j * 8;
            uint4 wv;
            wv.x = pk_bf16(xls[(c0 + 0) * LXP + pp], xls[(c0 + 1) * LXP + pp]);
            wv.y = pk_bf16(xls[(c0 + 2) * LXP + pp], xls[(c0 + 3) * LXP + pp]);
            wv.z = pk_bf16(xls[(c0 + 4) * LXP + pp], xls[(c0 + 5) * LXP + pp]);
            wv.w = pk_bf16(xls[(c0 + 6) * LXP + pp], xls[(c0 + 7) * LXP + pp]);
            *(uint4*)(dst + j * 8) = wv;
        }
    }
}

// scan + fill with shadow folding
__global__ __launch_bounds__(256) void fill_bins(
    const int* __restrict__ bincount, const int* __restrict__ pixmask,
    int* __restrict__ idx, int* __restrict__ pixaux,
    int* __restrict__ tileMask, int* __restrict__ tileBase,
    int* __restrict__ ntiles)
{
    __shared__ int spc[256], snt[256], bb[256];
    __shared__ int sbase[NSH][256];
    const int tid = threadIdx.x;
    int c = 0;
    #pragma unroll
    for (int s = 0; s < NSH; ++s) {
        sbase[s][tid] = c;
        c += bincount[s * 256 + tid];       // coalesced per s
    }
    const int nt = (c + 63) >> 6;
    const int pc = nt << 6;
    spc[tid] = pc; snt[tid] = nt;
    __syncthreads();
    #pragma unroll
    for (int off = 1; off < 256; off <<= 1) {
        int a = (tid >= off) ? spc[tid - off] : 0;
        int d = (tid >= off) ? snt[tid - off] : 0;
        __syncthreads();
        spc[tid] += a; snt[tid] += d;
        __syncthreads();
    }
    const int base = spc[tid] - pc;
    bb[tid] = base;
    if (blockIdx.x == 0) {
        const int tstart = snt[tid] - nt;
        for (int j = 0; j < nt; ++j) {
            tileMask[tstart + j] = tid;
            tileBase[tstart + j] = base + (j << 6);
        }
        if (tid == 255) ntiles[0] = snt[255];
    }
    __syncthreads();

    const int gp = blockIdx.x * 256 + tid;   // grid exactly 73728
    int mask = pixmask[gp];
    int shadow = (gp >> 6) & (NSH - 1);      // router block = gp/64
    int slot = bb[mask] + sbase[shadow][mask] + pixaux[gp];
    idx[slot] = gp;
    pixaux[gp] = slot;                        // reuse as pixslot
}

// moe: exact r7 structure (single-buffer hs, 2 barriers/chunk, proven 203us)
__global__ __launch_bounds__(256, 3) void moe_sparse(
    const unsigned short* __restrict__ xT, const int* __restrict__ idx,
    const float* __restrict__ pixw3,
    const int* __restrict__ tileMask, const int* __restrict__ tileBase,
    const int* __restrict__ ntiles,
    const unsigned short* __restrict__ wbf,
    const float* __restrict__ sb1, const float* __restrict__ sb2,
    const float* __restrict__ eb1, const float* __restrict__ eb2,
    unsigned short* __restrict__ outT)
{
    __shared__ unsigned short xs[64 * LDX];
    __shared__ unsigned short hs[64 * LDH];
    __shared__ float wls[64 * 4];

    const int t = blockIdx.x;
    if (t >= ntiles[0]) return;
    const int mask = tileMask[t];
    const int base = tileBase[t];
    const int tid = threadIdx.x;

    {
        const int p = tid >> 2, q = tid & 3;
        const int gp = idx[base + p];
        const unsigned short* src = xT + (size_t)gp * 128 + q * 32;
        unsigned short* dst = &xs[p * LDX + q * 32];
        #pragma unroll
        for (int j = 0; j < 4; ++j)
            *(u16x8*)(dst + j * 8) = *(const u16x8*)(src + j * 8);
        if (q == 0) {
            wls[p * 4 + 0] = pixw3[gp * 3 + 0];
            wls[p * 4 + 1] = pixw3[gp * 3 + 1];
            wls[p * 4 + 2] = pixw3[gp * 3 + 2];
        }
    }
    __syncthreads();

    int el[3];
    { int n = 0;
      #pragma unroll
      for (int e = 0; e < 8; ++e) if ((mask >> e) & 1) { if (n < 3) el[n] = e; ++n; } }

    const int wave = tid >> 6;
    const int lr = tid & 15;
    const int lq = (tid >> 4) & 3;

    const f32x4 vzero = {0.f, 0.f, 0.f, 0.f};
    f32x4 fin[2][4];
    #pragma unroll
    for (int t2 = 0; t2 < 2; ++t2)
        #pragma unroll
        for (int nt2 = 0; nt2 < 4; ++nt2) fin[t2][nt2] = vzero;

    for (int pass = 0; pass < 4; ++pass) {
        const unsigned short* w1; const unsigned short* w2;
        const float* b1; const float* b2;
        if (pass == 0) { w1 = wbf; b1 = sb1; w2 = wbf + 65536; b2 = sb2; }
        else {
            int e = el[pass - 1];
            w1 = wbf + 131072 + (size_t)e * (512 * 128);  b1 = eb1 + e * 512;
            w2 = wbf + 655360 + (size_t)e * (128 * 512);  b2 = eb2 + e * 128;
        }

        f32x4 tmp[2][4];
        #pragma unroll
        for (int t2 = 0; t2 < 2; ++t2)
            #pragma unroll
            for (int nt2 = 0; nt2 < 4; ++nt2) tmp[t2][nt2] = vzero;

        for (int chunk = 0; chunk < 4; ++chunk) {
            u16x8 w1f[2][4];
            #pragma unroll
            for (int t2 = 0; t2 < 2; ++t2) {
                const int hid0 = chunk * 128 + wave * 32 + t2 * 16;
                const u16x8* wr = (const u16x8*)(w1 + (size_t)(hid0 + lr) * 128) + lq;
                #pragma unroll
                for (int ks = 0; ks < 4; ++ks) w1f[t2][ks] = wr[ks * 4];
            }
            f32x4 acc[2][4];
            #pragma unroll
            for (int t2 = 0; t2 < 2; ++t2)
                #pragma unroll
                for (int nt2 = 0; nt2 < 4; ++nt2) acc[t2][nt2] = vzero;
            #pragma unroll
            for (int ks = 0; ks < 4; ++ks) {
                #pragma unroll
                for (int nt2 = 0; nt2 < 4; ++nt2) {
                    u16x8 xf = *(const u16x8*)&xs[(nt2 * 16 + lr) * LDX + ks * 32 + lq * 8];
                    acc[0][nt2] = mfma16(w1f[0][ks], xf, acc[0][nt2]);
                    acc[1][nt2] = mfma16(w1f[1][ks], xf, acc[1][nt2]);
                }
            }
            #pragma unroll
            for (int t2 = 0; t2 < 2; ++t2) {
                const int hl = wave * 32 + t2 * 16 + lq * 4;
                const f32x4 b1v = *(const f32x4*)&b1[chunk * 128 + hl];
                #pragma unroll
                for (int nt2 = 0; nt2 < 4; ++nt2) {
                    float g0 = fast_gelu(acc[t2][nt2][0] + b1v[0]);
                    float g1 = fast_gelu(acc[t2][nt2][1] + b1v[1]);
                    float g2 = fast_gelu(acc[t2][nt2][2] + b1v[2]);
                    float g3 = fast_gelu(acc[t2][nt2][3] + b1v[3]);
                    uint2 wv = {pk_bf16(g0, g1), pk_bf16(g2, g3)};
                    *(uint2*)&hs[(nt2 * 16 + lr) * LDH + hl] = wv;
                }
            }
            __syncthreads();
            u16x8 w2f[2][4];
            #pragma unroll
            for (int t2 = 0; t2 < 2; ++t2) {
                const int c0 = wave * 32 + t2 * 16;
                const u16x8* wr = (const u16x8*)(w2 + (size_t)(c0 + lr) * 512 + chunk * 128) + lq;
                #pragma unroll
                for (int ks = 0; ks < 4; ++ks) w2f[t2][ks] = wr[ks * 4];
            }
            #pragma unroll
            for (int ks = 0; ks < 4; ++ks) {
                #pragma unroll
                for (int nt2 = 0; nt2 < 4; ++nt2) {
                    u16x8 hb = *(const u16x8*)&hs[(nt2 * 16 + lr) * LDH + ks * 32 + lq * 8];
                    tmp[0][nt2] = mfma16(w2f[0][ks], hb, tmp[0][nt2]);
                    tmp[1][nt2] = mfma16(w2f[1][ks], hb, tmp[1][nt2]);
                }
            }
            __syncthreads();
        }
        float wtv[4];
        #pragma unroll
        for (int nt2 = 0; nt2 < 4; ++nt2)
            wtv[nt2] = (pass == 0) ? 1.0f : wls[(nt2 * 16 + lr) * 4 + (pass - 1)];
        #pragma unroll
        for (int t2 = 0; t2 < 2; ++t2) {
            const f32x4 b2v = *(const f32x4*)&b2[wave * 32 + t2 * 16 + lq * 4];
            #pragma unroll
            for (int nt2 = 0; nt2 < 4; ++nt2)
                #pragma unroll
                for (int r = 0; r < 4; ++r)
                    fin[t2][nt2][r] += wtv[nt2] * (tmp[t2][nt2][r] + b2v[r]);
        }
    }

    #pragma unroll
    for (int t2 = 0; t2 < 2; ++t2)
        #pragma unroll
        for (int nt2 = 0; nt2 < 4; ++nt2) {
            unsigned short* dst = outT + ((size_t)(base + nt2 * 16 + lr)) * 128
                                + wave * 32 + t2 * 16 + lq * 4;
            uint2 wv = {pk_bf16(fin[t2][nt2][0], fin[t2][nt2][1]),
                        pk_bf16(fin[t2][nt2][2], fin[t2][nt2][3])};
            *(uint2*)dst = wv;
        }
}

__global__ __launch_bounds__(256) void final_add(
    const float* __restrict__ x, const unsigned short* __restrict__ outT,
    const int* __restrict__ pixslot, const float* __restrict__ accum,
    float* __restrict__ out)
{
    if (blockIdx.x == 0 && threadIdx.x == 0) {   // fold shadows + aux loss
        float a16[16];
        #pragma unroll
        for (int i = 0; i < 16; ++i) {
            float s = 0.f;
            #pragma unroll
            for (int sh = 0; sh < NSH; ++sh) s += accum[sh * 16 + i];
            a16[i] = s;
        }
        float aux = 0.f;
        #pragma unroll
        for (int e = 0; e < 8; ++e) aux += a16[e] * a16[8 + e];
        out[9437184] = 8.0f * aux / ((float)NPIX * (float)NPIX);
    }
    __shared__ unsigned short ts[64 * 133];
    const int blk = blockIdx.x;
    const int b = blk / 144;
    const int p0 = (blk - b * 144) * 64;
    const int tid = threadIdx.x;
    {
        const int p = tid >> 2, q = tid & 3;
        const int slot = pixslot[blk * 64 + p];
        const unsigned short* src = outT + (size_t)slot * 128 + q * 32;
        unsigned short* dst = &ts[p * 133 + q * 32];
        #pragma unroll
        for (int j = 0; j < 4; ++j)
            *(u16x8*)(dst + j * 8) = *(const u16x8*)(src + j * 8);
    }
    __syncthreads();
    const int pl = tid & 63, cq = tid >> 6;
    const float* xb = x + (size_t)b * 128 * HWP + p0;
    float* ob = out + (size_t)b * 128 * HWP + p0;
    #pragma unroll
    for (int c0 = 0; c0 < 128; c0 += 4) {
        int c = c0 + cq;
        ob[(size_t)c * HWP + pl] = xb[(size_t)c * HWP + pl] + bf2f(ts[pl * 133 + c]);
    }
}

extern "C" void kernel_launch(void* const* d_in, const int* in_sizes, int n_in,
                              void* d_out, int out_size, void* d_ws, size_t ws_size,
                              hipStream_t stream)
{
    const float* x   = (const float*)d_in[0];
    const float* sw1 = (const float*)d_in[1];
    const float* sb1 = (const float*)d_in[2];
    const float* sw2 = (const float*)d_in[3];
    const float* sb2 = (const float*)d_in[4];
    const float* gw  = (const float*)d_in[5];
    const float* gb  = (const float*)d_in[6];
    const float* ew1 = (const float*)d_in[7];
    const float* eb1 = (const float*)d_in[8];
    const float* ew2 = (const float*)d_in[9];
    const float* eb2 = (const float*)d_in[10];
    float* out = (float*)d_out;
    char* ws = (char*)d_ws;

    const size_t o_wbf     = 0;                       // 2359296
    const size_t o_xT      = 2359296;                 // 18874368
    const size_t o_outT    = o_xT + 18874368;         // 19791872
    const size_t o_pixmask = o_outT + 19791872;       // 294912
    const size_t o_pixw3   = o_pixmask + 294912;      // 884736
    const size_t o_pixaux  = o_pixw3 + 884736;        // 294912
    const size_t o_tmask   = o_pixaux + 294912;       // 4864
    const size_t o_tbase   = o_tmask + 4864;          // 4864
    const size_t o_idx     = o_tbase + 4864;          // 309248  <-- memset from here
    const size_t o_cnt     = o_idx + 309248;          // NSH*256*4 = 16384
    const size_t o_ntiles  = o_cnt + 16384;           // 16
    const size_t o_accum   = o_ntiles + 16;           // NSH*16*4 = 1024
    const size_t MEMSET_SZ = 309248 + 16384 + 16 + 1024;

    unsigned short* wbf  = (unsigned short*)(ws + o_wbf);
    unsigned short* xT   = (unsigned short*)(ws + o_xT);
    unsigned short* outT = (unsigned short*)(ws + o_outT);
    int* pixmask  = (int*)(ws + o_pixmask);
    float* pixw3  = (float*)(ws + o_pixw3);
    int* pixaux   = (int*)(ws + o_pixaux);
    int* tmask    = (int*)(ws + o_tmask);
    int* tbase    = (int*)(ws + o_tbase);
    int* idx      = (int*)(ws + o_idx);
    int* bincount = (int*)(ws + o_cnt);
    int* ntiles   = (int*)(ws + o_ntiles);
    float* accum  = (float*)(ws + o_accum);

    (void)hipMemsetAsync(ws + o_idx, 0, MEMSET_SZ, stream);
    router_fused<<<1152, 256, 0, stream>>>(x, gw, gb, sw1, sw2, ew1, ew2, wbf,
                                           xT, pixmask, pixw3, pixaux, bincount, accum);
    fill_bins<<<288, 256, 0, stream>>>(bincount, pixmask, idx, pixaux,
                                       tmask, tbase, ntiles);
    moe_sparse<<<MAXTILES, 256, 0, stream>>>(xT, idx, pixw3, tmask, tbase, ntiles,
        wbf, sb1, sb2, eb1, eb2, outT);
    final_add<<<1152, 256, 0, stream>>>(x, outT, pixaux, accum, out);
}